// Round 6
// baseline (22779.260 us; speedup 1.0000x reference)
//
#include <hip/hip_runtime.h>
#include <hip/hip_bf16.h>

// Problem constants: S=512, B=256, E=256, H=256, V=50000
#define SS 512
#define BB 256
#define EE 256
#define HH 256
#define VV 50000
#define NCH 512          // 512 chains = 256 batch x 2 towers
#define VR 16            // emb rows per block in embw GEMM

// Cooperative-grid decomposition: 32 groups x 8 unit-slices = 256 WGs (1/CU).
#define NGRP 32
#define NSLC 8

__device__ __forceinline__ float sigf(float x) { return 1.f / (1.f + __expf(-x)); }
__device__ __forceinline__ float tanhf_fast(float x) { return 1.f - 2.f / (__expf(2.f * x) + 1.f); }

// Pack W[4H][K] row-major into Wp[k][t] = float4{W[t][k], W[H+t][k], W[2H+t][k], W[3H+t][k]}
__global__ void pack_w4(const float* __restrict__ W, float4* __restrict__ Wp, int K) {
    int idx = blockIdx.x * blockDim.x + threadIdx.x;
    if (idx >= K * HH) return;
    int k = idx >> 8, t = idx & 255;
    Wp[idx] = make_float4(W[(0 * HH + t) * K + k], W[(1 * HH + t) * K + k],
                          W[(2 * HH + t) * K + k], W[(3 * HH + t) * K + k]);
}

__global__ void pack_b(const float* __restrict__ bi, const float* __restrict__ bh,
                       float4* __restrict__ bp) {
    int t = threadIdx.x;
    bp[t] = make_float4(bi[0 * HH + t] + bh[0 * HH + t], bi[1 * HH + t] + bh[1 * HH + t],
                        bi[2 * HH + t] + bh[2 * HH + t], bi[3 * HH + t] + bh[3 * HH + t]);
}

__global__ void transpose_w1(const float* __restrict__ W1, float* __restrict__ W1T) {
    int idx = blockIdx.x * blockDim.x + threadIdx.x;
    if (idx >= 2 * HH * HH) return;
    int k = idx >> 8, j = idx & 255;
    W1T[idx] = W1[j * (2 * HH) + k];
}

__global__ void zero_cnt(int* __restrict__ cnt) {
    int t = threadIdx.x;
    if (t < NGRP) cnt[t] = 0;
}

// embWp[v][t] = float4 over 4 gates of (emb[v] @ W_ih^T + b_ih + b_hh)
__global__ __launch_bounds__(256) void embw_kernel(const float* __restrict__ emb,
                                                   const float4* __restrict__ Wip,
                                                   const float4* __restrict__ bp,
                                                   float4* __restrict__ embWp) {
    __shared__ float se[VR][EE];
    int t = threadIdx.x;
    int v0 = blockIdx.x * VR;
    for (int r = 0; r < VR; ++r) se[r][t] = emb[(size_t)(v0 + r) * EE + t];
    __syncthreads();
    float4 bb = bp[t];
    float4 acc[VR];
#pragma unroll
    for (int r = 0; r < VR; ++r) acc[r] = bb;
#pragma unroll 2
    for (int k = 0; k < EE; ++k) {
        float4 w = Wip[k * HH + t];
#pragma unroll
        for (int r = 0; r < VR; ++r) {
            float x = se[r][k];
            acc[r].x += w.x * x; acc[r].y += w.y * x;
            acc[r].z += w.z * x; acc[r].w += w.w * x;
        }
    }
    for (int r = 0; r < VR; ++r) embWp[(size_t)(v0 + r) * HH + t] = acc[r];
}

// ---------------------------------------------------------------------------
// Cooperative persistent LSTM. Group g (32 groups) owns chains [16g,16g+16).
// WG (g,u) holds W_hh slice for units [32u,32u+32) in LDS (128KB) permanently.
// Group's 8 WGs are bids {g, g+32, ...} == g (mod 8) -> same XCD. h exchanged
// via double-buffered hbuf + device fences + per-group atomic arrive counter.
// SAFETY: spin has a sticky bail (~0.3s once, then free-runs) so the kernel
// terminates quickly even if co-residency is ever violated (no GPU hang).
// Thread t: j=t&31 (unit), ks=(t>>5)&1 (k-half), mg=t>>6 (chain quad).
// ---------------------------------------------------------------------------
__global__ __launch_bounds__(256, 1) void lstm_coop(
    const int* __restrict__ s1, const int* __restrict__ s2,
    const float4* __restrict__ Whp, const float4* __restrict__ embWp,
    const float* __restrict__ h0_1, const float* __restrict__ c0_1,
    const float* __restrict__ h0_2, const float* __restrict__ c0_2,
    float* __restrict__ feat, float* __restrict__ hbuf, int* __restrict__ cnt) {
    __shared__ float4 w4s[256 * 32];   // 128KB: [k][j] 4 gates of unit 32u+j
    __shared__ float4 hls4[256 * 4];   // 16KB:  [k][mg] h of chains 4mg..4mg+3

    const int bid = blockIdx.x;
    const int g = bid & (NGRP - 1);
    const int u = bid >> 5;            // unit-slice
    const int t = threadIdx.x;
    const int j = t & 31, ks = (t >> 5) & 1, mg = t >> 6;
    const int u32j = u * 32 + j;

    // Load W_hh slice into LDS (once).
    for (int idx = t; idx < 256 * 32; idx += 256)
        w4s[idx] = Whp[(idx >> 5) * HH + u * 32 + (idx & 31)];

    const bool tw2 = g >= 16;
    const float* h0x = tw2 ? h0_2 : h0_1;
    const float* c0x = tw2 ? c0_2 : c0_1;
    const int* tp = tw2 ? s2 : s1;
    const int gb = (g & 15) * 16;  // batch base of this group's chains

    // h0 -> LDS (layout: f32 elem e = k*16 + cc  <=>  h[chain cc][k])
    float* hptr = (float*)hls4;
#pragma unroll
    for (int q = 0; q < 16; ++q) {
        int e = t + q * 256;
        hptr[e] = h0x[(gb + (e & 15)) * HH + (e >> 4)];
    }
    float c[4];
#pragma unroll
    for (int i = 0; i < 4; ++i) c[i] = c0x[(gb + mg * 4 + i) * HH + u32j];
    __syncthreads();

    // x-projection prefetch pipeline: this thread covers chains mg*4+2ks+{0,1}
    const int bq0 = gb + mg * 4 + 2 * ks;
    float4 pfv[2]; int tnx[2];
    {
        int tk0 = tp[0 * BB + bq0], tk1 = tp[0 * BB + bq0 + 1];
        pfv[0] = embWp[(size_t)tk0 * HH + u32j];
        pfv[1] = embWp[(size_t)tk1 * HH + u32j];
        tnx[0] = tp[1 * BB + bq0];
        tnx[1] = tp[1 * BB + bq0 + 1];
    }

    const float4* wp = w4s + ks * 128 * 32 + j;
    const float4* hp = hls4 + ks * 128 * 4 + mg;
    const int chg0 = g * 16 + mg * 4;  // global chain base (== tower*256+b)
    int dead = 0;                      // sticky bail flag (thread 0 only uses it)

    for (int s = 0; s < SS; ++s) {
        // Issue next-step gathers; they retire under the FMA loop (vmcnt FIFO).
        float4 pf2[2]; int t2[2];
        pf2[0] = embWp[(size_t)tnx[0] * HH + u32j];
        pf2[1] = embWp[(size_t)tnx[1] * HH + u32j];
        int sn = (s + 2 < SS) ? s + 2 : SS - 1;
        t2[0] = tp[sn * BB + bq0];
        t2[1] = tp[sn * BB + bq0 + 1];

        float4 a0 = {0, 0, 0, 0}, a1 = {0, 0, 0, 0}, a2 = {0, 0, 0, 0}, a3 = {0, 0, 0, 0};
#pragma unroll 4
        for (int kk = 0; kk < 128; ++kk) {
            float4 w = wp[kk * 32];
            float4 h4 = hp[kk * 4];
            a0.x += w.x * h4.x; a0.y += w.y * h4.x; a0.z += w.z * h4.x; a0.w += w.w * h4.x;
            a1.x += w.x * h4.y; a1.y += w.y * h4.y; a1.z += w.z * h4.y; a1.w += w.w * h4.y;
            a2.x += w.x * h4.z; a2.y += w.y * h4.z; a2.z += w.z * h4.z; a2.w += w.w * h4.z;
            a3.x += w.x * h4.w; a3.y += w.y * h4.w; a3.z += w.z * h4.w; a3.w += w.w * h4.w;
        }
        // Add x-projection pre-combine: each k-half adds its 2 chains once.
        if (ks == 0) {
            a0.x += pfv[0].x; a0.y += pfv[0].y; a0.z += pfv[0].z; a0.w += pfv[0].w;
            a1.x += pfv[1].x; a1.y += pfv[1].y; a1.z += pfv[1].z; a1.w += pfv[1].w;
        } else {
            a2.x += pfv[0].x; a2.y += pfv[0].y; a2.z += pfv[0].z; a2.w += pfv[0].w;
            a3.x += pfv[1].x; a3.y += pfv[1].y; a3.z += pfv[1].z; a3.w += pfv[1].w;
        }
        // Combine k-halves (lane <-> lane+32); both halves end identical.
        a0.x += __shfl_xor(a0.x, 32); a0.y += __shfl_xor(a0.y, 32);
        a0.z += __shfl_xor(a0.z, 32); a0.w += __shfl_xor(a0.w, 32);
        a1.x += __shfl_xor(a1.x, 32); a1.y += __shfl_xor(a1.y, 32);
        a1.z += __shfl_xor(a1.z, 32); a1.w += __shfl_xor(a1.w, 32);
        a2.x += __shfl_xor(a2.x, 32); a2.y += __shfl_xor(a2.y, 32);
        a2.z += __shfl_xor(a2.z, 32); a2.w += __shfl_xor(a2.w, 32);
        a3.x += __shfl_xor(a3.x, 32); a3.y += __shfl_xor(a3.y, 32);
        a3.z += __shfl_xor(a3.z, 32); a3.w += __shfl_xor(a3.w, 32);

        float hn[4];
        {
            float ig, fg, gg, og;
            ig = sigf(a0.x); fg = sigf(a0.y); gg = tanhf_fast(a0.z); og = sigf(a0.w);
            c[0] = fg * c[0] + ig * gg; hn[0] = og * tanhf_fast(c[0]);
            ig = sigf(a1.x); fg = sigf(a1.y); gg = tanhf_fast(a1.z); og = sigf(a1.w);
            c[1] = fg * c[1] + ig * gg; hn[1] = og * tanhf_fast(c[1]);
            ig = sigf(a2.x); fg = sigf(a2.y); gg = tanhf_fast(a2.z); og = sigf(a2.w);
            c[2] = fg * c[2] + ig * gg; hn[2] = og * tanhf_fast(c[2]);
            ig = sigf(a3.x); fg = sigf(a3.y); gg = tanhf_fast(a3.z); og = sigf(a3.w);
            c[3] = fg * c[3] + ig * gg; hn[3] = og * tanhf_fast(c[3]);
        }
        // Publish h^{s+1} slice (coalesced; ks==0 lanes only).
        float* hdst = hbuf + ((s + 1) & 1) * (NCH * HH);
        if (ks == 0) {
            hdst[(chg0 + 0) * HH + u32j] = hn[0];
            hdst[(chg0 + 1) * HH + u32j] = hn[1];
            hdst[(chg0 + 2) * HH + u32j] = hn[2];
            hdst[(chg0 + 3) * HH + u32j] = hn[3];
        }
        __threadfence();   // release: make stores visible at device scope
        __syncthreads();
        if (t == 0) {
            atomicAdd(&cnt[g], 1);
            int tgt = NSLC * (s + 1);
            if (!dead) {
                long it = 0;
                while (__hip_atomic_load(&cnt[g], __ATOMIC_RELAXED,
                                         __HIP_MEMORY_SCOPE_AGENT) < tgt) {
                    if (++it >= 4000000L) { dead = 1; break; }  // ~0.3s once, then free-run
                    __builtin_amdgcn_s_sleep(2);
                }
            }
        }
        __syncthreads();
        __threadfence();   // acquire: invalidate stale cached hbuf lines
        // Copy group's h^{s+1} -> LDS.
        const float* hsrc = hbuf + ((s + 1) & 1) * (NCH * HH) + (g * 16) * HH;
#pragma unroll
        for (int q = 0; q < 16; ++q) {
            int e = t + q * 256;
            hptr[e] = hsrc[(e & 15) * HH + (e >> 4)];
        }
        __syncthreads();
        pfv[0] = pf2[0]; pfv[1] = pf2[1];
        tnx[0] = t2[0]; tnx[1] = t2[1];
    }

    if (u == 0) {
#pragma unroll
        for (int q = 0; q < 16; ++q) {
            int e = t + q * 256;
            feat[(size_t)(g * 16 + (e & 15)) * HH + (e >> 4)] = hptr[e];
        }
    }
}

// ---------------------------------------------------------------------------
// Fallback streaming LSTM if ws can't hold the embW table.
// ---------------------------------------------------------------------------
#define NBF 4
__global__ __launch_bounds__(256, 1) void lstm_stream(
    const int* __restrict__ s1, const int* __restrict__ s2, const float* __restrict__ emb,
    const float4* __restrict__ Whp, const float4* __restrict__ Wip,
    const float4* __restrict__ bp,
    const float* __restrict__ h0_1, const float* __restrict__ c0_1,
    const float* __restrict__ h0_2, const float* __restrict__ c0_2,
    float* __restrict__ feat) {
    __shared__ float hs[NBF][HH];
    __shared__ float xs[NBF][EE];
    int t = threadIdx.x;
    int ch0 = blockIdx.x * NBF;
    float c[NBF];
    int bat[NBF];
    const int* toks[NBF];
#pragma unroll
    for (int nb = 0; nb < NBF; ++nb) {
        int ch = ch0 + nb;
        bool t2 = ch >= BB;
        int b = t2 ? ch - BB : ch;
        bat[nb] = b;
        toks[nb] = t2 ? s2 : s1;
        hs[nb][t] = (t2 ? h0_2 : h0_1)[b * HH + t];
        c[nb] = (t2 ? c0_2 : c0_1)[b * HH + t];
    }
    __syncthreads();
    for (int s = 0; s < SS; ++s) {
        float4 acc[NBF];
        float4 bb = bp[t];
#pragma unroll
        for (int nb = 0; nb < NBF; ++nb) {
            int tok = toks[nb][s * BB + bat[nb]];
            xs[nb][t] = emb[(size_t)tok * EE + t];
            acc[nb] = bb;
        }
        __syncthreads();
#pragma unroll 4
        for (int k = 0; k < EE; ++k) {
            float4 w = Wip[k * HH + t];
#pragma unroll
            for (int nb = 0; nb < NBF; ++nb) {
                float x = xs[nb][k];
                acc[nb].x += w.x * x; acc[nb].y += w.y * x;
                acc[nb].z += w.z * x; acc[nb].w += w.w * x;
            }
        }
#pragma unroll 8
        for (int k = 0; k < HH; ++k) {
            float4 w = Whp[k * HH + t];
#pragma unroll
            for (int nb = 0; nb < NBF; ++nb) {
                float hk = hs[nb][k];
                acc[nb].x += w.x * hk; acc[nb].y += w.y * hk;
                acc[nb].z += w.z * hk; acc[nb].w += w.w * hk;
            }
        }
        float hnew[NBF];
#pragma unroll
        for (int nb = 0; nb < NBF; ++nb) {
            float ig = sigf(acc[nb].x), fg = sigf(acc[nb].y);
            float gg = tanhf_fast(acc[nb].z), og = sigf(acc[nb].w);
            c[nb] = fg * c[nb] + ig * gg;
            hnew[nb] = og * tanhf_fast(c[nb]);
        }
        __syncthreads();
#pragma unroll
        for (int nb = 0; nb < NBF; ++nb) hs[nb][t] = hnew[nb];
        __syncthreads();
    }
#pragma unroll
    for (int nb = 0; nb < NBF; ++nb) feat[(size_t)(ch0 + nb) * HH + t] = hs[nb][t];
}

__global__ __launch_bounds__(256) void head_kernel(const float* __restrict__ feat,
                                                   const float* __restrict__ W1T,
                                                   const float* __restrict__ b1,
                                                   const float* __restrict__ W2,
                                                   const float* __restrict__ b2,
                                                   float* __restrict__ out) {
    __shared__ float f[2 * HH];
    __shared__ float r0[256], r1[256];
    int j = threadIdx.x;
    int b = blockIdx.x;
    f[j] = feat[(size_t)b * HH + j];
    f[HH + j] = feat[(size_t)(BB + b) * HH + j];
    __syncthreads();
    float acc = b1[j];
#pragma unroll 4
    for (int k = 0; k < 2 * HH; ++k) acc += f[k] * W1T[k * HH + j];
    r0[j] = acc * W2[0 * HH + j];
    r1[j] = acc * W2[1 * HH + j];
    __syncthreads();
    for (int st = 128; st > 0; st >>= 1) {
        if (j < st) { r0[j] += r0[j + st]; r1[j] += r1[j + st]; }
        __syncthreads();
    }
    if (j == 0) {
        out[b * 2 + 0] = r0[0] + b2[0];
        out[b * 2 + 1] = r1[0] + b2[1];
    }
}

extern "C" void kernel_launch(void* const* d_in, const int* in_sizes, int n_in,
                              void* d_out, int out_size, void* d_ws, size_t ws_size,
                              hipStream_t stream) {
    const int* s1 = (const int*)d_in[0];
    const int* s2 = (const int*)d_in[1];
    const float* emb = (const float*)d_in[2];
    const float* W_ih = (const float*)d_in[3];
    const float* W_hh = (const float*)d_in[4];
    const float* b_ih = (const float*)d_in[5];
    const float* b_hh = (const float*)d_in[6];
    const float* h0_1 = (const float*)d_in[7];
    const float* c0_1 = (const float*)d_in[8];
    const float* h0_2 = (const float*)d_in[9];
    const float* c0_2 = (const float*)d_in[10];
    const float* W1 = (const float*)d_in[11];
    const float* b1 = (const float*)d_in[12];
    const float* W2 = (const float*)d_in[13];
    const float* b2 = (const float*)d_in[14];
    float* out = (float*)d_out;

    char* ws = (char*)d_ws;
    size_t off = 0;
    auto alloc = [&](size_t bytes) {
        void* p = ws + off;
        off += (bytes + 255) & ~(size_t)255;
        return p;
    };
    float4* Whp = (float4*)alloc((size_t)HH * HH * sizeof(float4));   // 1MB
    float4* Wip = (float4*)alloc((size_t)EE * HH * sizeof(float4));   // 1MB
    float4* bp = (float4*)alloc(HH * sizeof(float4));
    float* W1T = (float*)alloc((size_t)2 * HH * HH * sizeof(float));  // 512KB
    float* feat = (float*)alloc((size_t)NCH * HH * sizeof(float));    // 512KB
    float* hbuf = (float*)alloc((size_t)2 * NCH * HH * sizeof(float)); // 1MB
    int* cnt = (int*)alloc(NGRP * sizeof(int));
    size_t embw_bytes = (size_t)VV * HH * sizeof(float4);             // 204.8MB
    bool pre = (ws_size >= off + embw_bytes);
    float4* embWp = pre ? (float4*)alloc(embw_bytes) : nullptr;

    pack_w4<<<(HH * HH + 255) / 256, 256, 0, stream>>>(W_ih, Wip, EE);
    pack_w4<<<(HH * HH + 255) / 256, 256, 0, stream>>>(W_hh, Whp, HH);
    pack_b<<<1, 256, 0, stream>>>(b_ih, b_hh, bp);
    transpose_w1<<<(2 * HH * HH + 255) / 256, 256, 0, stream>>>(W1, W1T);

    if (pre) {
        zero_cnt<<<1, 128, 0, stream>>>(cnt);
        embw_kernel<<<VV / VR, 256, 0, stream>>>(emb, Wip, bp, embWp);
        lstm_coop<<<NGRP * NSLC, 256, 0, stream>>>(s1, s2, Whp, embWp,
                                                   h0_1, c0_1, h0_2, c0_2,
                                                   feat, hbuf, cnt);
    } else {
        lstm_stream<<<NCH / NBF, 256, 0, stream>>>(s1, s2, emb, Whp, Wip, bp,
                                                   h0_1, c0_1, h0_2, c0_2, feat);
    }
    head_kernel<<<BB, 256, 0, stream>>>(feat, W1T, b1, W2, b2, out);
}

// Round 8
// 5476.170 us; speedup vs baseline: 4.1597x; 4.1597x over previous
//
#include <hip/hip_runtime.h>
#include <hip/hip_bf16.h>

// Problem constants: S=512, B=256, E=256, H=256, V=50000
#define SS 512
#define BB 256
#define EE 256
#define HH 256
#define VV 50000
#define NCH 512          // 512 chains = 256 batch x 2 towers
#define VR 16            // emb rows per block in embw GEMM

// Cooperative-grid decomposition: 32 groups x 8 unit-slices = 256 WGs (1/CU).
// Groups are self-organized per-XCD at runtime: 4 groups of 8 WGs per XCD.
#define NGRP 32
#define NSLC 8

// ctrl[] layout (ints, in ws, zeroed every launch):
#define CTRL_CNT 0       // [0..31]  per-group heavy-path arrive counters
#define CTRL_START 32    //          startup grid barrier counter
#define CTRL_UNSAFE 33   //          grid-uniform fallback flag
#define CTRL_CLAIMG 34   //          global slot claim counter
#define CTRL_CLAIMX 40   // [40..47] per-XCD slot claim counters
#define CTRL_FLAGS 64    // [64..)   fast-path flags: (gid*8+u)*16 stride (64B apart)
#define CTRL_N (64 + NGRP * NSLC * 16)

__device__ __forceinline__ float sigf(float x) { return 1.f / (1.f + __expf(-x)); }
__device__ __forceinline__ float tanhf_fast(float x) { return 1.f - 2.f / (__expf(2.f * x) + 1.f); }

// Pack W[4H][K] row-major into Wp[k][t] = float4{W[t][k], W[H+t][k], W[2H+t][k], W[3H+t][k]}
__global__ void pack_w4(const float* __restrict__ W, float4* __restrict__ Wp, int K) {
    int idx = blockIdx.x * blockDim.x + threadIdx.x;
    if (idx >= K * HH) return;
    int k = idx >> 8, t = idx & 255;
    Wp[idx] = make_float4(W[(0 * HH + t) * K + k], W[(1 * HH + t) * K + k],
                          W[(2 * HH + t) * K + k], W[(3 * HH + t) * K + k]);
}

__global__ void pack_b(const float* __restrict__ bi, const float* __restrict__ bh,
                       float4* __restrict__ bp) {
    int t = threadIdx.x;
    bp[t] = make_float4(bi[0 * HH + t] + bh[0 * HH + t], bi[1 * HH + t] + bh[1 * HH + t],
                        bi[2 * HH + t] + bh[2 * HH + t], bi[3 * HH + t] + bh[3 * HH + t]);
}

__global__ void transpose_w1(const float* __restrict__ W1, float* __restrict__ W1T) {
    int idx = blockIdx.x * blockDim.x + threadIdx.x;
    if (idx >= 2 * HH * HH) return;
    int k = idx >> 8, j = idx & 255;
    W1T[idx] = W1[j * (2 * HH) + k];
}

__global__ void zero_ctrl(int* __restrict__ p) {
    int i = blockIdx.x * blockDim.x + threadIdx.x;
    if (i < CTRL_N) p[i] = 0;
}

// embWp[v][t] = float4 over 4 gates of (emb[v] @ W_ih^T + b_ih + b_hh)
__global__ __launch_bounds__(256) void embw_kernel(const float* __restrict__ emb,
                                                   const float4* __restrict__ Wip,
                                                   const float4* __restrict__ bp,
                                                   float4* __restrict__ embWp) {
    __shared__ float se[VR][EE];
    int t = threadIdx.x;
    int v0 = blockIdx.x * VR;
    for (int r = 0; r < VR; ++r) se[r][t] = emb[(size_t)(v0 + r) * EE + t];
    __syncthreads();
    float4 bb = bp[t];
    float4 acc[VR];
#pragma unroll
    for (int r = 0; r < VR; ++r) acc[r] = bb;
#pragma unroll 2
    for (int k = 0; k < EE; ++k) {
        float4 w = Wip[k * HH + t];
#pragma unroll
        for (int r = 0; r < VR; ++r) {
            float x = se[r][k];
            acc[r].x += w.x * x; acc[r].y += w.y * x;
            acc[r].z += w.z * x; acc[r].w += w.w * x;
        }
    }
    for (int r = 0; r < VR; ++r) embWp[(size_t)(v0 + r) * HH + t] = acc[r];
}

// ---------------------------------------------------------------------------
// Cooperative persistent LSTM with XCD-local exchange.
// Startup: WG reads its physical XCC_ID, claims a slot on that XCD; exactly
// 32 WGs/XCD (144KB LDS => 1 WG/CU; grid==256==CU count) form 4 groups of 8.
// Group g owns chains [16g,16g+16); WG (g,u) holds W_hh rows for units
// [32u,32u+32) in LDS permanently.
// Exchange buffer hbuf: [parity][gid][4096 floats] in (k*16+chain) order --
// writers store ONE coalesced float4 per ks==0 thread; readers do fully
// lane-linear dword loads straight into the LDS mirror.
// Per-step exchange (fast path, same-XCD guaranteed by construction):
//   plain h stores (write-through to XCD L2) -> __syncthreads (vmcnt drain)
//   -> t0 volatile flag store -> t0 polls 8 peer flags volatile (sc0) ->
//   volatile reload of group h from L2. No fences, no L2 writeback/inv.
// Fallback (unsafe flag, grid-uniform): proven device-fence protocol.
// Thread t: j=t&31 (unit), ks=(t>>5)&1 (k-half), mg=t>>6 (chain quad).
// ---------------------------------------------------------------------------
__global__ __launch_bounds__(256, 1) void lstm_coop(
    const int* __restrict__ s1, const int* __restrict__ s2,
    const float4* __restrict__ Whp, const float4* __restrict__ embWp,
    const float* __restrict__ h0_1, const float* __restrict__ c0_1,
    const float* __restrict__ h0_2, const float* __restrict__ c0_2,
    float* __restrict__ feat, float* __restrict__ hbuf, int* __restrict__ ctrl) {
    __shared__ float4 w4s[256 * 32];   // 128KB: [k][j] 4 gates of unit 32u+j
    __shared__ float4 hls4[256 * 4];   // 16KB:  [k][cc] h of the 16 chains
    __shared__ int shi[4];             // gid, u, unsafe

    const int t = threadIdx.x;
    const int j = t & 31, ks = (t >> 5) & 1, mg = t >> 6;

    // ---- startup: claim slot on my physical XCD, grid barrier, pick scheme --
    if (t == 0) {
        // s_getreg HW_REG_XCC_ID (id=20), offset 0, size 32 -> imm 20|(31<<11)
        int my_xcd = (int)__builtin_amdgcn_s_getreg(63508) & 7;
        int slot = atomicAdd(&ctrl[CTRL_CLAIMX + my_xcd], 1);
        int wall = atomicAdd(&ctrl[CTRL_CLAIMG], 1);
        if (slot >= 32)
            __hip_atomic_fetch_or(&ctrl[CTRL_UNSAFE], 1, __ATOMIC_RELAXED,
                                  __HIP_MEMORY_SCOPE_AGENT);
        __hip_atomic_fetch_add(&ctrl[CTRL_START], 1, __ATOMIC_RELEASE,
                               __HIP_MEMORY_SCOPE_AGENT);
        long it = 0;
        while (__hip_atomic_load(&ctrl[CTRL_START], __ATOMIC_ACQUIRE,
                                 __HIP_MEMORY_SCOPE_AGENT) < NGRP * NSLC) {
            if (++it >= 3000000L) break;  // bounded: never hang the queue
            __builtin_amdgcn_s_sleep(2);
        }
        int uns = __hip_atomic_load(&ctrl[CTRL_UNSAFE], __ATOMIC_ACQUIRE,
                                    __HIP_MEMORY_SCOPE_AGENT);
        if (uns) { shi[0] = wall >> 3; shi[1] = wall & 7; }
        else     { shi[0] = my_xcd * 4 + (slot >> 3); shi[1] = slot & 7; }
        shi[2] = uns;
    }
    __syncthreads();
    const int gid = shi[0];
    const int u = shi[1];
    const bool safe = (shi[2] == 0);
    const int u32j = u * 32 + j;

    // ---- load W_hh slice into LDS (once) ------------------------------------
    for (int idx = t; idx < 256 * 32; idx += 256)
        w4s[idx] = Whp[(idx >> 5) * HH + u * 32 + (idx & 31)];

    const bool tw2 = gid >= 16;
    const float* h0x = tw2 ? h0_2 : h0_1;
    const float* c0x = tw2 ? c0_2 : c0_1;
    const int* tp = tw2 ? s2 : s1;
    const int gb = (gid & 15) * 16;  // batch base of this group's chains

    // h0 -> LDS (layout: f32 elem e = k*16 + cc  <=>  h[chain cc][k])
    float* hptr = (float*)hls4;
#pragma unroll
    for (int q = 0; q < 16; ++q) {
        int e = t + q * 256;
        hptr[e] = h0x[(gb + (e & 15)) * HH + (e >> 4)];
    }
    float c[4];
#pragma unroll
    for (int i = 0; i < 4; ++i) c[i] = c0x[(gb + mg * 4 + i) * HH + u32j];
    __syncthreads();

    // x-projection prefetch pipeline: this thread covers chains mg*4+2ks+{0,1}
    const int bq0 = gb + mg * 4 + 2 * ks;
    float4 pfv[2]; int tnx[2];
    {
        int tk0 = tp[0 * BB + bq0], tk1 = tp[0 * BB + bq0 + 1];
        pfv[0] = embWp[(size_t)tk0 * HH + u32j];
        pfv[1] = embWp[(size_t)tk1 * HH + u32j];
        tnx[0] = tp[1 * BB + bq0];
        tnx[1] = tp[1 * BB + bq0 + 1];
    }

    const float4* wp = w4s + ks * 128 * 32 + j;
    const float4* hp = hls4 + ks * 128 * 4 + mg;
    volatile int* fl = (volatile int*)(ctrl + CTRL_FLAGS + gid * NSLC * 16);
    int dead = 0;  // sticky bail (t0 only)

    for (int s = 0; s < SS; ++s) {
        // Issue next-step gathers; they retire under the FMA loop (vmcnt FIFO).
        float4 pf2[2]; int t2[2];
        pf2[0] = embWp[(size_t)tnx[0] * HH + u32j];
        pf2[1] = embWp[(size_t)tnx[1] * HH + u32j];
        int sn = (s + 2 < SS) ? s + 2 : SS - 1;
        t2[0] = tp[sn * BB + bq0];
        t2[1] = tp[sn * BB + bq0 + 1];

        float4 a0 = {0, 0, 0, 0}, a1 = {0, 0, 0, 0}, a2 = {0, 0, 0, 0}, a3 = {0, 0, 0, 0};
#pragma unroll 4
        for (int kk = 0; kk < 128; ++kk) {
            float4 w = wp[kk * 32];
            float4 h4 = hp[kk * 4];
            a0.x += w.x * h4.x; a0.y += w.y * h4.x; a0.z += w.z * h4.x; a0.w += w.w * h4.x;
            a1.x += w.x * h4.y; a1.y += w.y * h4.y; a1.z += w.z * h4.y; a1.w += w.w * h4.y;
            a2.x += w.x * h4.z; a2.y += w.y * h4.z; a2.z += w.z * h4.z; a2.w += w.w * h4.z;
            a3.x += w.x * h4.w; a3.y += w.y * h4.w; a3.z += w.z * h4.w; a3.w += w.w * h4.w;
        }
        // Add x-projection pre-combine: each k-half adds its 2 chains once.
        if (ks == 0) {
            a0.x += pfv[0].x; a0.y += pfv[0].y; a0.z += pfv[0].z; a0.w += pfv[0].w;
            a1.x += pfv[1].x; a1.y += pfv[1].y; a1.z += pfv[1].z; a1.w += pfv[1].w;
        } else {
            a2.x += pfv[0].x; a2.y += pfv[0].y; a2.z += pfv[0].z; a2.w += pfv[0].w;
            a3.x += pfv[1].x; a3.y += pfv[1].y; a3.z += pfv[1].z; a3.w += pfv[1].w;
        }
        // Combine k-halves (lane <-> lane+32); both halves end identical.
        a0.x += __shfl_xor(a0.x, 32); a0.y += __shfl_xor(a0.y, 32);
        a0.z += __shfl_xor(a0.z, 32); a0.w += __shfl_xor(a0.w, 32);
        a1.x += __shfl_xor(a1.x, 32); a1.y += __shfl_xor(a1.y, 32);
        a1.z += __shfl_xor(a1.z, 32); a1.w += __shfl_xor(a1.w, 32);
        a2.x += __shfl_xor(a2.x, 32); a2.y += __shfl_xor(a2.y, 32);
        a2.z += __shfl_xor(a2.z, 32); a2.w += __shfl_xor(a2.w, 32);
        a3.x += __shfl_xor(a3.x, 32); a3.y += __shfl_xor(a3.y, 32);
        a3.z += __shfl_xor(a3.z, 32); a3.w += __shfl_xor(a3.w, 32);

        float hn[4];
        {
            float ig, fg, gg, og;
            ig = sigf(a0.x); fg = sigf(a0.y); gg = tanhf_fast(a0.z); og = sigf(a0.w);
            c[0] = fg * c[0] + ig * gg; hn[0] = og * tanhf_fast(c[0]);
            ig = sigf(a1.x); fg = sigf(a1.y); gg = tanhf_fast(a1.z); og = sigf(a1.w);
            c[1] = fg * c[1] + ig * gg; hn[1] = og * tanhf_fast(c[1]);
            ig = sigf(a2.x); fg = sigf(a2.y); gg = tanhf_fast(a2.z); og = sigf(a2.w);
            c[2] = fg * c[2] + ig * gg; hn[2] = og * tanhf_fast(c[2]);
            ig = sigf(a3.x); fg = sigf(a3.y); gg = tanhf_fast(a3.z); og = sigf(a3.w);
            c[3] = fg * c[3] + ig * gg; hn[3] = og * tanhf_fast(c[3]);
        }
        // Publish h^{s+1} slice: ONE coalesced float4 store per ks==0 thread
        // into the (k*16+cc)-ordered per-group buffer. Plain stores land in
        // the XCD L2 (write-through L1); __syncthreads drains vmcnt.
        float* hx = hbuf + ((s + 1) & 1) * (NGRP * 16 * HH) + gid * (16 * HH);
        if (ks == 0) {
            *((float4*)(hx + u32j * 16 + mg * 4)) =
                make_float4(hn[0], hn[1], hn[2], hn[3]);
        }
        __syncthreads();  // all stores drained (vmcnt 0) before flag/arrive
        if (safe) {
            // XCD-local: flag + volatile polls, all traffic stays in this L2.
            if (t == 0) {
                fl[u * 16] = s + 1;
                if (!dead) {
                    long it = 0;
                    for (;;) {
                        int ok = 1;
#pragma unroll
                        for (int x = 0; x < NSLC; ++x) ok &= (fl[x * 16] >= s + 1);
                        if (ok) break;
                        if (++it >= 400000L) { dead = 1; break; }  // bounded
                    }
                }
            }
        } else {
            // Proven device-scope fallback (slow, only if self-organize failed).
            __threadfence();
            if (t == 0) {
                atomicAdd(&ctrl[CTRL_CNT + gid], 1);
                int tgt = NSLC * (s + 1);
                if (!dead) {
                    long it = 0;
                    while (__hip_atomic_load(&ctrl[CTRL_CNT + gid], __ATOMIC_RELAXED,
                                             __HIP_MEMORY_SCOPE_AGENT) < tgt) {
                        if (++it >= 4000000L) { dead = 1; break; }
                        __builtin_amdgcn_s_sleep(2);
                    }
                }
            }
        }
        __syncthreads();
        if (!safe) __threadfence();
        // Reload group's h^{s+1} -> LDS. Lane-linear volatile (sc0) loads
        // bypass our L1 and read the XCD-shared L2; layout already matches LDS.
        const volatile float* hsrc = (const volatile float*)hx;
#pragma unroll
        for (int q = 0; q < 16; ++q) {
            int e = t + q * 256;
            hptr[e] = hsrc[e];
        }
        __syncthreads();
        pfv[0] = pf2[0]; pfv[1] = pf2[1];
        tnx[0] = t2[0]; tnx[1] = t2[1];
    }

    if (u == 0) {
#pragma unroll
        for (int q = 0; q < 16; ++q) {
            int e = t + q * 256;
            feat[(size_t)(gid * 16 + (e & 15)) * HH + (e >> 4)] = hptr[e];
        }
    }
}

// ---------------------------------------------------------------------------
// Fallback streaming LSTM if ws can't hold the embW table.
// ---------------------------------------------------------------------------
#define NBF 4
__global__ __launch_bounds__(256, 1) void lstm_stream(
    const int* __restrict__ s1, const int* __restrict__ s2, const float* __restrict__ emb,
    const float4* __restrict__ Whp, const float4* __restrict__ Wip,
    const float4* __restrict__ bp,
    const float* __restrict__ h0_1, const float* __restrict__ c0_1,
    const float* __restrict__ h0_2, const float* __restrict__ c0_2,
    float* __restrict__ feat) {
    __shared__ float hs[NBF][HH];
    __shared__ float xs[NBF][EE];
    int t = threadIdx.x;
    int ch0 = blockIdx.x * NBF;
    float c[NBF];
    int bat[NBF];
    const int* toks[NBF];
#pragma unroll
    for (int nb = 0; nb < NBF; ++nb) {
        int ch = ch0 + nb;
        bool t2 = ch >= BB;
        int b = t2 ? ch - BB : ch;
        bat[nb] = b;
        toks[nb] = t2 ? s2 : s1;
        hs[nb][t] = (t2 ? h0_2 : h0_1)[b * HH + t];
        c[nb] = (t2 ? c0_2 : c0_1)[b * HH + t];
    }
    __syncthreads();
    for (int s = 0; s < SS; ++s) {
        float4 acc[NBF];
        float4 bb = bp[t];
#pragma unroll
        for (int nb = 0; nb < NBF; ++nb) {
            int tok = toks[nb][s * BB + bat[nb]];
            xs[nb][t] = emb[(size_t)tok * EE + t];
            acc[nb] = bb;
        }
        __syncthreads();
#pragma unroll 4
        for (int k = 0; k < EE; ++k) {
            float4 w = Wip[k * HH + t];
#pragma unroll
            for (int nb = 0; nb < NBF; ++nb) {
                float x = xs[nb][k];
                acc[nb].x += w.x * x; acc[nb].y += w.y * x;
                acc[nb].z += w.z * x; acc[nb].w += w.w * x;
            }
        }
#pragma unroll 8
        for (int k = 0; k < HH; ++k) {
            float4 w = Whp[k * HH + t];
#pragma unroll
            for (int nb = 0; nb < NBF; ++nb) {
                float hk = hs[nb][k];
                acc[nb].x += w.x * hk; acc[nb].y += w.y * hk;
                acc[nb].z += w.z * hk; acc[nb].w += w.w * hk;
            }
        }
        float hnew[NBF];
#pragma unroll
        for (int nb = 0; nb < NBF; ++nb) {
            float ig = sigf(acc[nb].x), fg = sigf(acc[nb].y);
            float gg = tanhf_fast(acc[nb].z), og = sigf(acc[nb].w);
            c[nb] = fg * c[nb] + ig * gg;
            hnew[nb] = og * tanhf_fast(c[nb]);
        }
        __syncthreads();
#pragma unroll
        for (int nb = 0; nb < NBF; ++nb) hs[nb][t] = hnew[nb];
        __syncthreads();
    }
#pragma unroll
    for (int nb = 0; nb < NBF; ++nb) feat[(size_t)(ch0 + nb) * HH + t] = hs[nb][t];
}

__global__ __launch_bounds__(256) void head_kernel(const float* __restrict__ feat,
                                                   const float* __restrict__ W1T,
                                                   const float* __restrict__ b1,
                                                   const float* __restrict__ W2,
                                                   const float* __restrict__ b2,
                                                   float* __restrict__ out) {
    __shared__ float f[2 * HH];
    __shared__ float r0[256], r1[256];
    int j = threadIdx.x;
    int b = blockIdx.x;
    f[j] = feat[(size_t)b * HH + j];
    f[HH + j] = feat[(size_t)(BB + b) * HH + j];
    __syncthreads();
    float acc = b1[j];
#pragma unroll 4
    for (int k = 0; k < 2 * HH; ++k) acc += f[k] * W1T[k * HH + j];
    r0[j] = acc * W2[0 * HH + j];
    r1[j] = acc * W2[1 * HH + j];
    __syncthreads();
    for (int st = 128; st > 0; st >>= 1) {
        if (j < st) { r0[j] += r0[j + st]; r1[j] += r1[j + st]; }
        __syncthreads();
    }
    if (j == 0) {
        out[b * 2 + 0] = r0[0] + b2[0];
        out[b * 2 + 1] = r1[0] + b2[1];
    }
}

extern "C" void kernel_launch(void* const* d_in, const int* in_sizes, int n_in,
                              void* d_out, int out_size, void* d_ws, size_t ws_size,
                              hipStream_t stream) {
    const int* s1 = (const int*)d_in[0];
    const int* s2 = (const int*)d_in[1];
    const float* emb = (const float*)d_in[2];
    const float* W_ih = (const float*)d_in[3];
    const float* W_hh = (const float*)d_in[4];
    const float* b_ih = (const float*)d_in[5];
    const float* b_hh = (const float*)d_in[6];
    const float* h0_1 = (const float*)d_in[7];
    const float* c0_1 = (const float*)d_in[8];
    const float* h0_2 = (const float*)d_in[9];
    const float* c0_2 = (const float*)d_in[10];
    const float* W1 = (const float*)d_in[11];
    const float* b1 = (const float*)d_in[12];
    const float* W2 = (const float*)d_in[13];
    const float* b2 = (const float*)d_in[14];
    float* out = (float*)d_out;

    char* ws = (char*)d_ws;
    size_t off = 0;
    auto alloc = [&](size_t bytes) {
        void* p = ws + off;
        off += (bytes + 255) & ~(size_t)255;
        return p;
    };
    float4* Whp = (float4*)alloc((size_t)HH * HH * sizeof(float4));   // 1MB
    float4* Wip = (float4*)alloc((size_t)EE * HH * sizeof(float4));   // 1MB
    float4* bp = (float4*)alloc(HH * sizeof(float4));
    float* W1T = (float*)alloc((size_t)2 * HH * HH * sizeof(float));  // 512KB
    float* feat = (float*)alloc((size_t)NCH * HH * sizeof(float));    // 512KB
    float* hbuf = (float*)alloc((size_t)2 * NGRP * 16 * HH * sizeof(float)); // 1MB
    int* ctrl = (int*)alloc(CTRL_N * sizeof(int));                    // 20KB
    size_t embw_bytes = (size_t)VV * HH * sizeof(float4);             // 204.8MB
    bool pre = (ws_size >= off + embw_bytes);
    float4* embWp = pre ? (float4*)alloc(embw_bytes) : nullptr;

    pack_w4<<<(HH * HH + 255) / 256, 256, 0, stream>>>(W_ih, Wip, EE);
    pack_w4<<<(HH * HH + 255) / 256, 256, 0, stream>>>(W_hh, Whp, HH);
    pack_b<<<1, 256, 0, stream>>>(b_ih, b_hh, bp);
    transpose_w1<<<(2 * HH * HH + 255) / 256, 256, 0, stream>>>(W1, W1T);

    if (pre) {
        zero_ctrl<<<(CTRL_N + 255) / 256, 256, 0, stream>>>(ctrl);
        embw_kernel<<<VV / VR, 256, 0, stream>>>(emb, Wip, bp, embWp);
        lstm_coop<<<NGRP * NSLC, 256, 0, stream>>>(s1, s2, Whp, embWp,
                                                   h0_1, c0_1, h0_2, c0_2,
                                                   feat, hbuf, ctrl);
    } else {
        lstm_stream<<<NCH / NBF, 256, 0, stream>>>(s1, s2, emb, Whp, Wip, bp,
                                                   h0_1, c0_1, h0_2, c0_2, feat);
    }
    head_kernel<<<BB, 256, 0, stream>>>(feat, W1T, b1, W2, b2, out);
}